// Round 13
// baseline (432.097 us; speedup 1.0000x reference)
//
#include <hip/hip_runtime.h>

#define NN 100000
#define NE 1000000
#define D 128
#define ALPHA 0.5f

// ---------------- workspace layout (bytes), all 16B-aligned ----------------
// z       [NN][256] f32 : 0           (102,400,000)
// W2_big  [256][128] f32: 102,400,000 (+131,072)
// bias    [128] f32     : 102,531,072 (+512)
// cnt     [NN] i32      : 102,531,584 (+400,000)
// start   [NN] i32      : 102,931,584 (+400,000)
// binCnt / binBase / binCursor: 103,331,584 (+2048 each)
// buf     [2*NE] i32    : 103,337,728 (+8,000,000)
// rec4    [2*NE] i32    : 111,337,728 (+8,000,000) => need 119,337,728
#define OFF_W2     102400000UL
#define OFF_BIAS   102531072UL
#define OFF_CNT    102531584UL
#define OFF_START  102931584UL
#define OFF_BINC   103331584UL
#define OFF_BINB   103333632UL
#define OFF_BINCUR 103335680UL
#define OFF_BUF    103337728UL
#define OFF_REC    111337728UL

#define NB  391      // bins of 256 nodes
#define EPB 2048     // edges per block in count/place

// ---------------------------------------------------------------------------
// K0: fused weight W2_big[k][j] (256 x 128) for out = z @ W2_big + bias.
// ---------------------------------------------------------------------------
__global__ __launch_bounds__(256) void build_w2b(const float* __restrict__ Wsd,
                                                 const float* __restrict__ Wds,
                                                 const float* __restrict__ bsd,
                                                 const float* __restrict__ bds,
                                                 float* __restrict__ W2,
                                                 float* __restrict__ bias) {
    int idx = blockIdx.x * 256 + threadIdx.x;   // 0..32767
    int k = idx >> 7;
    int j = idx & 127;
    float v;
    if (k < 128) v = ALPHA * Wsd[j * D + k];
    else         v = (1.0f - ALPHA) * Wds[j * D + (k - 128)];
    W2[idx] = v;
    if (idx < 128) bias[idx] = ALPHA * bsd[idx] + (1.0f - ALPHA) * bds[idx];
}

// ---------------------------------------------------------------------------
// CSR build via two-level counting sort (verified r9/r12).
//   rec = (keyLocal<<18) | (partner<<1) | half
//   buf entry = (partner<<1) | half
// ---------------------------------------------------------------------------
__global__ __launch_bounds__(512) void zero_bins(int* __restrict__ binCnt) {
    int i = threadIdx.x;
    if (i < NB) binCnt[i] = 0;
}

__global__ __launch_bounds__(256) void count_bins(const int* __restrict__ esrc,
                                                  const int* __restrict__ edst,
                                                  int* __restrict__ binCnt) {
    __shared__ int h[NB];
    int t = threadIdx.x;
    for (int i = t; i < NB; i += 256) h[i] = 0;
    __syncthreads();
    int e0 = blockIdx.x * EPB;
    for (int i = t; i < EPB; i += 256) {
        int e = e0 + i;
        if (e < NE) {
            atomicAdd(&h[edst[e] >> 8], 1);
            atomicAdd(&h[esrc[e] >> 8], 1);
        }
    }
    __syncthreads();
    for (int i = t; i < NB; i += 256)
        if (h[i]) atomicAdd(&binCnt[i], h[i]);
}

__global__ __launch_bounds__(256) void scan_bins(const int* __restrict__ binCnt,
                                                 int* __restrict__ binBase,
                                                 int* __restrict__ binCursor) {
    __shared__ int v[NB];
    int t = threadIdx.x;
    for (int i = t; i < NB; i += 256) v[i] = binCnt[i];
    __syncthreads();
    if (t == 0) {
        int acc = 0;
        for (int i = 0; i < NB; ++i) { int c = v[i]; v[i] = acc; acc += c; }
    }
    __syncthreads();
    for (int i = t; i < NB; i += 256) { binBase[i] = v[i]; binCursor[i] = v[i]; }
}

__global__ __launch_bounds__(256) void place_bins(const int* __restrict__ esrc,
                                                  const int* __restrict__ edst,
                                                  int* __restrict__ binCursor,
                                                  int* __restrict__ rec4) {
    __shared__ int h[NB];
    __shared__ int base[NB];
    __shared__ int lcur[NB];
    int t = threadIdx.x;
    for (int i = t; i < NB; i += 256) h[i] = 0;
    __syncthreads();
    int e0 = blockIdx.x * EPB;
    for (int i = t; i < EPB; i += 256) {
        int e = e0 + i;
        if (e < NE) {
            atomicAdd(&h[edst[e] >> 8], 1);
            atomicAdd(&h[esrc[e] >> 8], 1);
        }
    }
    __syncthreads();
    for (int i = t; i < NB; i += 256) {
        if (h[i]) base[i] = atomicAdd(&binCursor[i], h[i]);
        lcur[i] = 0;
    }
    __syncthreads();
    for (int i = t; i < EPB; i += 256) {
        int e = e0 + i;
        if (e < NE) {
            int s = esrc[e], d = edst[e];
            int bd = d >> 8, bs = s >> 8;
            int p1 = atomicAdd(&lcur[bd], 1);
            rec4[base[bd] + p1] = ((d & 255) << 18) | (s << 1);
            int p2 = atomicAdd(&lcur[bs], 1);
            rec4[base[bs] + p2] = ((s & 255) << 18) | (d << 1) | 1;
        }
    }
}

__global__ __launch_bounds__(256) void build_csr(const int* __restrict__ rec4,
                                                 const int* __restrict__ binBase,
                                                 const int* __restrict__ binCnt,
                                                 int* __restrict__ buf,
                                                 int* __restrict__ start,
                                                 int* __restrict__ cnt_out) {
    __shared__ int hc[256];
    __shared__ int st[256];
    int b = blockIdx.x;
    int t = threadIdx.x;
    int node0 = b << 8;
    int r0 = binBase[b];
    int rn = binCnt[b];

    hc[t] = 0;
    __syncthreads();
    for (int i = t; i < rn; i += 256)
        atomicAdd(&hc[rec4[r0 + i] >> 18], 1);
    __syncthreads();
    if (t == 0) {
        int acc = 0;
        for (int i = 0; i < 256; ++i) { st[i] = acc; acc += hc[i]; }
    }
    __syncthreads();
    int n = node0 + t;
    if (n < NN) {
        start[n]   = r0 + st[t];
        cnt_out[n] = hc[t];
    }
    hc[t] = st[t];          // reuse as local cursor
    __syncthreads();
    for (int i = t; i < rn; i += 256) {
        int r = rec4[r0 + i];
        int pos = atomicAdd(&hc[r >> 18], 1);
        buf[r0 + pos] = r & 0x3FFFF;    // (partner<<1) | half
    }
}

// ---------------------------------------------------------------------------
// K3: gather_z — 2 nodes per wave (32-lane groups), float4 per lane.
// Per group: 4-deep unrolled row-loads -> 8 independent 512B row streams in
// flight per wave (vs 4 in r12's 1-node/wave float2 version). Latency-bound
// fix: r12 counters showed HBM 49%, VALU 33% (neither saturated).
//   z[n][0:128]   = sum over half0 entries of x[partner]
//   z[n][128:256] = sum over half1 entries of x[partner]
// ---------------------------------------------------------------------------
__global__ __launch_bounds__(256) void gather_z(const int* __restrict__ start,
                                                const int* __restrict__ cnt,
                                                const int* __restrict__ buf,
                                                const float* __restrict__ x,
                                                float* __restrict__ z) {
    int wave = blockIdx.x * 4 + (threadIdx.x >> 6);
    int lane = threadIdx.x & 63;
    int g    = lane >> 5;              // group 0/1 within wave
    int gl   = lane & 31;              // lane within group
    int node = wave * 2 + g;
    if (node >= NN) return;            // exact fit: 12500*8 = 100000
    const int s0 = start[node];
    const int e0 = s0 + cnt[node];
    const int c4 = gl << 2;            // float offset within row

    float4 A = make_float4(0.f, 0.f, 0.f, 0.f);   // half 0
    float4 B = make_float4(0.f, 0.f, 0.f, 0.f);   // half 1

#define ACCUM(v, p) if ((v) & 1) { B.x += (p).x; B.y += (p).y; B.z += (p).z; B.w += (p).w; } \
                    else         { A.x += (p).x; A.y += (p).y; A.z += (p).z; A.w += (p).w; }

    int i = s0;
    for (; i + 4 <= e0; i += 4) {
        int v0 = buf[i], v1 = buf[i + 1], v2 = buf[i + 2], v3 = buf[i + 3];
        float4 p0 = *(const float4*)&x[(size_t)(v0 >> 1) * D + c4];
        float4 p1 = *(const float4*)&x[(size_t)(v1 >> 1) * D + c4];
        float4 p2 = *(const float4*)&x[(size_t)(v2 >> 1) * D + c4];
        float4 p3 = *(const float4*)&x[(size_t)(v3 >> 1) * D + c4];
        ACCUM(v0, p0) ACCUM(v1, p1) ACCUM(v2, p2) ACCUM(v3, p3)
    }
    for (; i < e0; ++i) {
        int v0 = buf[i];
        float4 p0 = *(const float4*)&x[(size_t)(v0 >> 1) * D + c4];
        ACCUM(v0, p0)
    }
#undef ACCUM

    *(float4*)&z[(size_t)node * 256 + c4]       = A;
    *(float4*)&z[(size_t)node * 256 + 128 + c4] = B;
}

// ---------------------------------------------------------------------------
// K4: transform_z GEMM (verified r12): out = z @ W2_big + bias.
// 64x64 tile / 256 threads, 4x4 register block, A-tile in LDS [64][132],
// K=256 as two 128-deep passes, B from L2-resident W2.
// ---------------------------------------------------------------------------
__global__ __launch_bounds__(256) void transform_z(const float* __restrict__ z,
                                                   const float* __restrict__ W2,
                                                   const float* __restrict__ bias,
                                                   float* __restrict__ out) {
    __shared__ float As[64][132];   // 33792 B
    const int tid  = threadIdx.x;
    const int brow = blockIdx.x * 64;
    const int bcol = blockIdx.y * 64;    // 0 or 64
    const int ty   = tid >> 4;
    const int tx   = tid & 15;

    float acc[4][4];
#pragma unroll
    for (int i = 0; i < 4; ++i)
#pragma unroll
        for (int j = 0; j < 4; ++j) acc[i][j] = 0.f;

    for (int kp = 0; kp < 2; ++kp) {
#pragma unroll
        for (int i = 0; i < 8; ++i) {
            int f   = tid + i * 256;
            int row = f >> 5;
            int kc  = (f & 31) << 2;
            float4 g = make_float4(0.f, 0.f, 0.f, 0.f);
            int grow = brow + row;
            if (grow < NN) g = *(const float4*)&z[(size_t)grow * 256 + kp * 128 + kc];
            *(float4*)&As[row][kc] = g;
        }
        __syncthreads();

#pragma unroll 2
        for (int k0 = 0; k0 < 128; k0 += 4) {
            float av[4][4], bv[4][4];
#pragma unroll
            for (int i = 0; i < 4; ++i) {
                float4 t = *(const float4*)&As[ty * 4 + i][k0];
                av[i][0] = t.x; av[i][1] = t.y; av[i][2] = t.z; av[i][3] = t.w;
            }
#pragma unroll
            for (int j = 0; j < 4; ++j) {
                float4 t = *(const float4*)&W2[(size_t)(kp * 128 + k0 + j) * 128 + bcol + tx * 4];
                bv[j][0] = t.x; bv[j][1] = t.y; bv[j][2] = t.z; bv[j][3] = t.w;
            }
#pragma unroll
            for (int i = 0; i < 4; ++i)
#pragma unroll
                for (int c = 0; c < 4; ++c)
#pragma unroll
                    for (int kk = 0; kk < 4; ++kk)
                        acc[i][c] += av[i][kk] * bv[kk][c];
        }
        __syncthreads();
    }

    float4 bb = *(const float4*)&bias[bcol + tx * 4];
#pragma unroll
    for (int i = 0; i < 4; ++i) {
        int row = brow + ty * 4 + i;
        if (row < NN) {
            float4 v = make_float4(acc[i][0] + bb.x, acc[i][1] + bb.y,
                                   acc[i][2] + bb.z, acc[i][3] + bb.w);
            *(float4*)&out[(size_t)row * D + bcol + tx * 4] = v;
        }
    }
}

// ---------------------------------------------------------------------------
extern "C" void kernel_launch(void* const* d_in, const int* in_sizes, int n_in,
                              void* d_out, int out_size, void* d_ws, size_t ws_size,
                              hipStream_t stream) {
    const float* x    = (const float*)d_in[0];
    const int*   esrc = (const int*)  d_in[1];
    const int*   edst = (const int*)  d_in[2];
    const float* Wsd  = (const float*)d_in[3];
    const float* bsd  = (const float*)d_in[4];
    const float* Wds  = (const float*)d_in[5];
    const float* bds  = (const float*)d_in[6];
    float* out = (float*)d_out;

    char*  ws       = (char*)d_ws;
    float* z        = (float*)ws;
    float* W2       = (float*)(ws + OFF_W2);
    float* bias     = (float*)(ws + OFF_BIAS);
    int*   cnt      = (int*)(ws + OFF_CNT);
    int*   start    = (int*)(ws + OFF_START);
    int*   binCnt   = (int*)(ws + OFF_BINC);
    int*   binBase  = (int*)(ws + OFF_BINB);
    int*   binCursor= (int*)(ws + OFF_BINCUR);
    int*   buf      = (int*)(ws + OFF_BUF);
    int*   rec4     = (int*)(ws + OFF_REC);

    const int nblk = (NE + EPB - 1) / EPB;   // 489

    build_w2b<<<128, 256, 0, stream>>>(Wsd, Wds, bsd, bds, W2, bias);
    zero_bins<<<1, 512, 0, stream>>>(binCnt);
    count_bins<<<nblk, 256, 0, stream>>>(esrc, edst, binCnt);
    scan_bins<<<1, 256, 0, stream>>>(binCnt, binBase, binCursor);
    place_bins<<<nblk, 256, 0, stream>>>(esrc, edst, binCursor, rec4);
    build_csr<<<NB, 256, 0, stream>>>(rec4, binBase, binCnt, buf, start, cnt);
    gather_z<<<12500, 256, 0, stream>>>(start, cnt, buf, x, z);  // 8 nodes/block
    transform_z<<<dim3((NN + 63) / 64, 2), 256, 0, stream>>>(z, W2, bias, out);
}